// Round 1
// baseline (438.456 us; speedup 1.0000x reference)
//
#include <hip/hip_runtime.h>
#include <hip/hip_bf16.h>

#define B 128
#define N 32
#define DO 128
#define NA 16
#define H 4
#define DK 64
#define DV 64
#define LN_EPS 1e-5f
#define NEG_SLOPE 0.01f

__device__ __forceinline__ float leaky(float x) {
    return x >= 0.f ? x : NEG_SLOPE * x;
}

// ---------------------------------------------------------------------------
// Kernel A: se = leaky(states@W_se+b_se); xa = leaky([states,actions]@W_sape+b);
//           xp = leaky([states,policies]@W_sape+b)
// grid: B*N blocks, 128 threads (thread = output column)
// ---------------------------------------------------------------------------
__global__ __launch_bounds__(128) void kA(
    const float* __restrict__ states, const float* __restrict__ policies,
    const float* __restrict__ actions, const float* __restrict__ W_se,
    const float* __restrict__ b_se, const float* __restrict__ W_sape,
    const float* __restrict__ b_sape,
    float* __restrict__ se, float* __restrict__ xa, float* __restrict__ xp)
{
    const int bn = blockIdx.x;
    const int t  = threadIdx.x;
    __shared__ float s_row[DO];
    __shared__ float a_row[NA];
    __shared__ float p_row[NA];
    s_row[t] = states[bn * DO + t];
    if (t < NA) { a_row[t] = actions[bn * NA + t]; p_row[t] = policies[bn * NA + t]; }
    __syncthreads();

    float acc_se = b_se[t];
    float acc_sp = 0.f;
    #pragma unroll 4
    for (int d = 0; d < DO; d++) {
        const float s = s_row[d];
        acc_se += s * W_se[d * 128 + t];
        acc_sp += s * W_sape[d * 128 + t];
    }
    float aa = b_sape[t] + acc_sp;
    float pp = aa;
    #pragma unroll
    for (int d = 0; d < NA; d++) {
        const float wv = W_sape[(DO + d) * 128 + t];
        aa += a_row[d] * wv;
        pp += p_row[d] * wv;
    }
    se[bn * 128 + t] = leaky(acc_se);
    xa[bn * 128 + t] = leaky(aa);
    xp[bn * 128 + t] = leaky(pp);
}

// ---------------------------------------------------------------------------
// Kernel B: per (b,h): q,k = se@Wq/Wk; scores=q.k'/8; softmax -> w (to d_out);
//           ava = xa@Wv; avp = xp@Wv; diff = avp-ava; S = w@ava
// grid: B*H blocks, 256 threads
// ---------------------------------------------------------------------------
__global__ __launch_bounds__(256) void kB(
    const float* __restrict__ se, const float* __restrict__ xa,
    const float* __restrict__ xp, const float* __restrict__ Wk,
    const float* __restrict__ Wq, const float* __restrict__ Wv,
    float* __restrict__ w_out, float* __restrict__ S, float* __restrict__ diff)
{
    const int bh = blockIdx.x;
    const int b  = bh >> 2;
    const int h  = bh & 3;
    const int t  = threadIdx.x;

    __shared__ float bufA[N * 128];    // se, then xp
    __shared__ float bufB[N * 128];    // xa
    __shared__ float q_s[N * DK];
    __shared__ float k_s[N * DK];
    __shared__ float ava_s[N * DV];
    __shared__ float sc[N * 33];       // scores -> softmax w (in place)

    for (int idx = t; idx < N * 128; idx += 256) {
        bufA[idx] = se[b * N * 128 + idx];
        bufB[idx] = xa[b * N * 128 + idx];
    }
    __syncthreads();

    const float* Wqh = Wq + h * 128 * DK;
    const float* Wkh = Wk + h * 128 * DK;
    const float* Wvh = Wv + h * 128 * DV;

    // q, k, ava
    for (int o = t; o < N * DK; o += 256) {
        const int i = o >> 6, e = o & 63;
        float aq = 0.f, ak = 0.f, av = 0.f;
        #pragma unroll 4
        for (int d = 0; d < 128; d++) {
            const float s = bufA[i * 128 + d];
            aq += s * Wqh[d * 64 + e];
            ak += s * Wkh[d * 64 + e];
            av += bufB[i * 128 + d] * Wvh[d * 64 + e];
        }
        q_s[o] = aq; k_s[o] = ak; ava_s[o] = av;
    }
    __syncthreads();

    // scores
    for (int o = t; o < N * N; o += 256) {
        const int i = o >> 5, j = o & 31;
        float a = 0.f;
        #pragma unroll 8
        for (int e = 0; e < 64; e++) a += q_s[i * 64 + e] * k_s[j * 64 + e];
        sc[i * 33 + j] = a * 0.125f;  // 1/sqrt(64)
    }
    __syncthreads();

    // softmax rows (threads 0..31), write w to output
    if (t < N) {
        const int i = t;
        float m = -1e30f;
        for (int j = 0; j < N; j++) m = fmaxf(m, sc[i * 33 + j]);
        float sum = 0.f;
        for (int j = 0; j < N; j++) {
            const float ev = __expf(sc[i * 33 + j] - m);
            sc[i * 33 + j] = ev;
            sum += ev;
        }
        const float inv = 1.f / sum;
        for (int j = 0; j < N; j++) {
            const float wv = sc[i * 33 + j] * inv;
            sc[i * 33 + j] = wv;
            w_out[(bh * N + i) * N + j] = wv;
        }
    }
    // overlap: load xp into bufA (no one reads bufA until next sync)
    for (int idx = t; idx < N * 128; idx += 256) bufA[idx] = xp[b * N * 128 + idx];
    __syncthreads();

    // avp -> diff; S = w @ ava
    for (int o = t; o < N * DV; o += 256) {
        const int i = o >> 6, e = o & 63;
        float ap = 0.f;
        #pragma unroll 4
        for (int d = 0; d < 128; d++) ap += bufA[i * 128 + d] * Wvh[d * 64 + e];
        diff[(bh * N + i) * DV + e] = ap - ava_s[o];
        float s = 0.f;
        #pragma unroll 8
        for (int k2 = 0; k2 < N; k2++) s += sc[i * 33 + k2] * ava_s[k2 * 64 + e];
        S[(bh * N + i) * DV + e] = s;
    }
}

// ---------------------------------------------------------------------------
// Kernel C: per (b,i): build mh[j][256] = LN(S[h,i,:] + w[h,i,j]*diff[h,j,:]),
//           value[b,i,j] = leaky(mh@W_f1) @ W_f2
// grid: B*N blocks, 256 threads
// ---------------------------------------------------------------------------
__global__ __launch_bounds__(256) void kC(
    const float* __restrict__ S, const float* __restrict__ diff,
    const float* __restrict__ w_all, const float* __restrict__ ln_g,
    const float* __restrict__ ln_b, const float* __restrict__ W_f1,
    const float* __restrict__ W_f2, float* __restrict__ value)
{
    const int bi = blockIdx.x;
    const int b  = bi >> 5;
    const int i  = bi & 31;
    const int t  = threadIdx.x;

    __shared__ float mh[N][260];       // 32 rows x 256 (+4 pad)
    __shared__ float wf1T[64][68];     // transposed W_f1 chunk: [e][c]
    __shared__ float S_s[256];
    __shared__ float w_s[128];
    __shared__ float lng[256];
    __shared__ float lnb[256];
    __shared__ float wf2[64];

    {
        const int h = t >> 6, e = t & 63;
        S_s[t] = S[((b * H + h) * N + i) * DV + e];
        lng[t] = ln_g[t];
        lnb[t] = ln_b[t];
        if (t < 128) {
            const int hh = t >> 5, j = t & 31;
            w_s[t] = w_all[((b * H + hh) * N + i) * N + j];
        }
        if (t < 64) wf2[t] = W_f2[t];
    }
    __syncthreads();

    // build mh: wave per j-offset, lane = e (64 lanes == Dv)
    const int wavej = t >> 6;
    const int e     = t & 63;
    for (int jb = 0; jb < 8; jb++) {
        const int j = jb * 4 + wavej;
        #pragma unroll
        for (int h = 0; h < H; h++) {
            float v = S_s[h * 64 + e] +
                      w_s[h * 32 + j] * diff[((b * H + h) * N + j) * DV + e];
            float s = v;
            #pragma unroll
            for (int m = 32; m; m >>= 1) s += __shfl_xor(s, m, 64);
            const float mu = s * (1.f / 64.f);
            const float d0 = v - mu;
            float s2 = d0 * d0;
            #pragma unroll
            for (int m = 32; m; m >>= 1) s2 += __shfl_xor(s2, m, 64);
            const float inv = rsqrtf(s2 * (1.f / 64.f) + LN_EPS);
            mh[j][h * 64 + e] = d0 * inv * lng[h * 64 + e] + lnb[h * 64 + e];
        }
    }

    // GEMM: [32 x 256] @ [256 x 64]; thread tile 4 rows x 2 cols
    const int tj = t >> 5;   // 0..7 -> rows tj*4 .. tj*4+3
    const int te = t & 31;   // cols te, te+32
    float acc[4][2] = {{0.f, 0.f}, {0.f, 0.f}, {0.f, 0.f}, {0.f, 0.f}};

    for (int kk = 0; kk < 4; kk++) {
        __syncthreads();  // mh ready (kk=0) / previous wf1T reads done (kk>0)
        for (int idx = t; idx < 4096; idx += 256) {
            const int c = idx >> 6, ee = idx & 63;
            wf1T[ee][c] = W_f1[(kk * 64 + c) * 64 + ee];
        }
        __syncthreads();
        #pragma unroll 4
        for (int c4 = 0; c4 < 16; c4++) {
            const int c = c4 * 4;
            const float4 a0 = *(const float4*)&mh[tj * 4 + 0][kk * 64 + c];
            const float4 a1 = *(const float4*)&mh[tj * 4 + 1][kk * 64 + c];
            const float4 a2 = *(const float4*)&mh[tj * 4 + 2][kk * 64 + c];
            const float4 a3 = *(const float4*)&mh[tj * 4 + 3][kk * 64 + c];
            const float4 w0 = *(const float4*)&wf1T[te][c];
            const float4 w1 = *(const float4*)&wf1T[te + 32][c];
            acc[0][0] += a0.x*w0.x + a0.y*w0.y + a0.z*w0.z + a0.w*w0.w;
            acc[0][1] += a0.x*w1.x + a0.y*w1.y + a0.z*w1.z + a0.w*w1.w;
            acc[1][0] += a1.x*w0.x + a1.y*w0.y + a1.z*w0.z + a1.w*w0.w;
            acc[1][1] += a1.x*w1.x + a1.y*w1.y + a1.z*w1.z + a1.w*w1.w;
            acc[2][0] += a2.x*w0.x + a2.y*w0.y + a2.z*w0.z + a2.w*w0.w;
            acc[2][1] += a2.x*w1.x + a2.y*w1.y + a2.z*w1.z + a2.w*w1.w;
            acc[3][0] += a3.x*w0.x + a3.y*w0.y + a3.z*w0.z + a3.w*w0.w;
            acc[3][1] += a3.x*w1.x + a3.y*w1.y + a3.z*w1.z + a3.w*w1.w;
        }
    }

    // epilogue: leaky + @W_f2 + reduce across te (32 lanes within half-wave)
    #pragma unroll
    for (int r = 0; r < 4; r++) {
        float p = leaky(acc[r][0]) * wf2[te] + leaky(acc[r][1]) * wf2[te + 32];
        #pragma unroll
        for (int m = 16; m; m >>= 1) p += __shfl_xor(p, m, 32);
        if (te == 0) value[bi * N + tj * 4 + r] = p;
    }
}

extern "C" void kernel_launch(void* const* d_in, const int* in_sizes, int n_in,
                              void* d_out, int out_size, void* d_ws, size_t ws_size,
                              hipStream_t stream)
{
    const float* states   = (const float*)d_in[0];
    const float* policies = (const float*)d_in[1];
    const float* actions  = (const float*)d_in[2];
    const float* W_se     = (const float*)d_in[3];
    const float* b_se     = (const float*)d_in[4];
    const float* W_sape   = (const float*)d_in[5];
    const float* b_sape   = (const float*)d_in[6];
    const float* Wk       = (const float*)d_in[7];
    const float* Wq       = (const float*)d_in[8];
    const float* Wv       = (const float*)d_in[9];
    const float* ln_g     = (const float*)d_in[10];
    const float* ln_b     = (const float*)d_in[11];
    const float* W_f1     = (const float*)d_in[12];
    const float* W_f2     = (const float*)d_in[13];

    float* out_value = (float*)d_out;                 // [B,N,N,1] = 131072
    float* out_w     = out_value + B * N * N;         // [B,H,N,N] = 524288

    float* ws   = (float*)d_ws;
    float* se   = ws;                                  // B*N*128 = 524288
    float* xa   = se + B * N * 128;                    // 524288
    float* xp   = xa + B * N * 128;                    // 524288
    float* Sbuf = xp + B * N * 128;                    // B*H*N*DV = 1048576
    float* dbuf = Sbuf + B * H * N * DV;               // 1048576

    kA<<<B * N, 128, 0, stream>>>(states, policies, actions, W_se, b_se,
                                  W_sape, b_sape, se, xa, xp);
    kB<<<B * H, 256, 0, stream>>>(se, xa, xp, Wk, Wq, Wv, out_w, Sbuf, dbuf);
    kC<<<B * N, 256, 0, stream>>>(Sbuf, dbuf, out_w, ln_g, ln_b, W_f1, W_f2,
                                  out_value);
}

// Round 2
// 211.521 us; speedup vs baseline: 2.0729x; 2.0729x over previous
//
#include <hip/hip_runtime.h>
#include <hip/hip_bf16.h>

#define B 128
#define N 32
#define DO 128
#define NA 16
#define H 4
#define DK 64
#define DV 64
#define LN_EPS 1e-5f
#define NEG_SLOPE 0.01f

__device__ __forceinline__ float leaky(float x) {
    return x >= 0.f ? x : NEG_SLOPE * x;
}

// ---------------------------------------------------------------------------
// kW: GW[h,c] = sum_e ln_g[h,e]*W_f1[h*64+e,c]; BW[c] = sum_he ln_b*W_f1
// one block, 256 threads
// ---------------------------------------------------------------------------
__global__ __launch_bounds__(256) void kW(
    const float* __restrict__ ln_g, const float* __restrict__ ln_b,
    const float* __restrict__ W_f1, float* __restrict__ GW, float* __restrict__ BW)
{
    const int t = threadIdx.x;
    const int h = t >> 6, c = t & 63;
    float acc = 0.f;
    for (int e = 0; e < 64; e++)
        acc += ln_g[h * 64 + e] * W_f1[(h * 64 + e) * 64 + c];
    GW[t] = acc;
    if (t < 64) {
        float a2 = 0.f;
        for (int r = 0; r < 256; r++) a2 += ln_b[r] * W_f1[r * 64 + t];
        BW[t] = a2;
    }
}

// ---------------------------------------------------------------------------
// Kernel A: se = leaky(states@W_se+b_se); xa/xp = leaky([states,act/pol]@W_sape+b)
// grid: B*N blocks, 128 threads
// ---------------------------------------------------------------------------
__global__ __launch_bounds__(128) void kA(
    const float* __restrict__ states, const float* __restrict__ policies,
    const float* __restrict__ actions, const float* __restrict__ W_se,
    const float* __restrict__ b_se, const float* __restrict__ W_sape,
    const float* __restrict__ b_sape,
    float* __restrict__ se, float* __restrict__ xa, float* __restrict__ xp)
{
    const int bn = blockIdx.x;
    const int t  = threadIdx.x;
    __shared__ float s_row[DO];
    __shared__ float a_row[NA];
    __shared__ float p_row[NA];
    s_row[t] = states[bn * DO + t];
    if (t < NA) { a_row[t] = actions[bn * NA + t]; p_row[t] = policies[bn * NA + t]; }
    __syncthreads();

    float acc_se = b_se[t];
    float acc_sp = 0.f;
    #pragma unroll 4
    for (int d = 0; d < DO; d++) {
        const float s = s_row[d];
        acc_se += s * W_se[d * 128 + t];
        acc_sp += s * W_sape[d * 128 + t];
    }
    float aa = b_sape[t] + acc_sp;
    float pp = aa;
    #pragma unroll
    for (int d = 0; d < NA; d++) {
        const float wv = W_sape[(DO + d) * 128 + t];
        aa += a_row[d] * wv;
        pp += p_row[d] * wv;
    }
    se[bn * 128 + t] = leaky(acc_se);
    xa[bn * 128 + t] = leaky(aa);
    xp[bn * 128 + t] = leaky(pp);
}

// ---------------------------------------------------------------------------
// Kernel B (per b,h; 512 threads):
//   q,k = se@Wq/Wk; scores; softmax -> w_out
//   ava = xa@Wv; avp = xp@Wv; diff = avp-ava; S = w@ava   (kept in LDS)
//   sums: sumS/sumS2 per i, sumD/sumD2 per j; dotSD[i,j] = S_i . diff_j
//   SG = S @ (g (.) W_f1h);  DG = diff @ (g (.) W_f1h)
// ---------------------------------------------------------------------------
#define RS 68  // padded row stride for S_s/diff_s (q_s/k_s)

__global__ __launch_bounds__(512) void kB(
    const float* __restrict__ se, const float* __restrict__ xa,
    const float* __restrict__ xp, const float* __restrict__ Wk,
    const float* __restrict__ Wq, const float* __restrict__ Wv,
    const float* __restrict__ W_f1, const float* __restrict__ ln_g,
    float* __restrict__ w_out,
    float* __restrict__ SG, float* __restrict__ DG,
    float* __restrict__ sumS, float* __restrict__ sumS2,
    float* __restrict__ sumD, float* __restrict__ sumD2,
    float* __restrict__ dotSD)
{
    const int bh = blockIdx.x;
    const int b  = bh >> 2;
    const int h  = bh & 3;
    const int t  = threadIdx.x;

    __shared__ float bufA[N * 128];    // se, then xp
    __shared__ float bufB[N * 128];    // xa, then Wg = g (.) W_f1h  [64e][64c]
    __shared__ float q_s[N * RS];      // q, then S
    __shared__ float k_s[N * RS];      // k, then diff
    __shared__ float ava_s[N * DV];
    __shared__ float sc[N * 33];
    __shared__ float g_s[64];

    // stage 0: load se, xa (float4)
    for (int idx = t; idx < N * 32; idx += 512) {
        ((float4*)bufA)[idx] = ((const float4*)(se + b * N * 128))[idx];
        ((float4*)bufB)[idx] = ((const float4*)(xa + b * N * 128))[idx];
    }
    if (t < 64) g_s[t] = ln_g[h * 64 + t];
    __syncthreads();

    const float* Wqh = Wq + h * 128 * DK;
    const float* Wkh = Wk + h * 128 * DK;
    const float* Wvh = Wv + h * 128 * DV;

    // stage 1: q, k, ava
    for (int o = t; o < N * DK; o += 512) {
        const int i = o >> 6, e = o & 63;
        float aq = 0.f, ak = 0.f, av = 0.f;
        #pragma unroll 4
        for (int d = 0; d < 128; d++) {
            const float s = bufA[i * 128 + d];
            aq += s * Wqh[d * 64 + e];
            ak += s * Wkh[d * 64 + e];
            av += bufB[i * 128 + d] * Wvh[d * 64 + e];
        }
        q_s[i * RS + e] = aq; k_s[i * RS + e] = ak; ava_s[i * 64 + e] = av;
    }
    __syncthreads();

    // stage 2: scores; concurrently reload bufA <- xp, bufB <- Wg
    for (int o = t; o < N * N; o += 512) {
        const int i = o >> 5, j = o & 31;
        float a = 0.f;
        #pragma unroll
        for (int e4 = 0; e4 < 16; e4++) {
            const float4 qv = *(const float4*)&q_s[i * RS + e4 * 4];
            const float4 kv = *(const float4*)&k_s[j * RS + e4 * 4];
            a += qv.x * kv.x + qv.y * kv.y + qv.z * kv.z + qv.w * kv.w;
        }
        sc[i * 33 + j] = a * 0.125f;
    }
    for (int idx = t; idx < N * 32; idx += 512)
        ((float4*)bufA)[idx] = ((const float4*)(xp + b * N * 128))[idx];
    for (int idx = t; idx < 4096; idx += 512) {
        const int e = idx >> 6, c = idx & 63;
        bufB[idx] = g_s[e] * W_f1[(h * 64 + e) * 64 + c];
    }
    __syncthreads();

    // stage 2b: softmax rows, write w
    if (t < N) {
        const int i = t;
        float m = -1e30f;
        for (int j = 0; j < N; j++) m = fmaxf(m, sc[i * 33 + j]);
        float sum = 0.f;
        for (int j = 0; j < N; j++) {
            const float ev = __expf(sc[i * 33 + j] - m);
            sc[i * 33 + j] = ev;
            sum += ev;
        }
        const float inv = 1.f / sum;
        for (int j = 0; j < N; j++) {
            const float wv = sc[i * 33 + j] * inv;
            sc[i * 33 + j] = wv;
            w_out[(bh * N + i) * N + j] = wv;
        }
    }
    __syncthreads();

    // stage 3: avp -> diff (k_s), S = w@ava (q_s)
    for (int o = t; o < N * DV; o += 512) {
        const int i = o >> 6, e = o & 63;
        float ap = 0.f;
        #pragma unroll 4
        for (int d = 0; d < 128; d++) ap += bufA[i * 128 + d] * Wvh[d * 64 + e];
        k_s[i * RS + e] = ap - ava_s[i * 64 + e];
        float s = 0.f;
        #pragma unroll 8
        for (int k2 = 0; k2 < N; k2++) s += sc[i * 33 + k2] * ava_s[k2 * 64 + e];
        q_s[i * RS + e] = s;
    }
    __syncthreads();

    // stage 4: row sums (64 rows: 32 of S, 32 of diff)
    if (t < 64) {
        const int r = t & 31;
        const float* src = (t < 32) ? (q_s + r * RS) : (k_s + r * RS);
        float s1 = 0.f, s2 = 0.f;
        #pragma unroll
        for (int e4 = 0; e4 < 16; e4++) {
            const float4 v = *(const float4*)&src[e4 * 4];
            s1 += v.x + v.y + v.z + v.w;
            s2 += v.x * v.x + v.y * v.y + v.z * v.z + v.w * v.w;
        }
        if (t < 32) { sumS[bh * N + r] = s1; sumS2[bh * N + r] = s2; }
        else        { sumD[bh * N + r] = s1; sumD2[bh * N + r] = s2; }
    }

    // stage 5: dotSD[i,j]
    for (int o = t; o < N * N; o += 512) {
        const int i = o >> 5, j = o & 31;
        float a = 0.f;
        #pragma unroll
        for (int e4 = 0; e4 < 16; e4++) {
            const float4 sv = *(const float4*)&q_s[i * RS + e4 * 4];
            const float4 dv = *(const float4*)&k_s[j * RS + e4 * 4];
            a += sv.x * dv.x + sv.y * dv.y + sv.z * dv.z + sv.w * dv.w;
        }
        dotSD[(bh * N + i) * N + j] = a;
    }

    // stage 6: SG = S@Wg, DG = diff@Wg  (1024 float4-quads, 2 per thread)
    for (int qo = t; qo < 1024; qo += 512) {
        const int isS = (qo < 512) ? 1 : 0;
        const int idx = qo & 511;
        const int r   = idx >> 4;
        const int c4  = (idx & 15) << 2;
        const float* src = isS ? (q_s + r * RS) : (k_s + r * RS);
        float4 acc = {0.f, 0.f, 0.f, 0.f};
        #pragma unroll 8
        for (int e = 0; e < 64; e++) {
            const float s = src[e];
            const float4 wv = *(const float4*)&bufB[e * 64 + c4];
            acc.x += s * wv.x; acc.y += s * wv.y;
            acc.z += s * wv.z; acc.w += s * wv.w;
        }
        float* dst = (isS ? SG : DG) + (bh * N + r) * 64 + c4;
        *(float4*)dst = acc;
    }
}

// ---------------------------------------------------------------------------
// Kernel C (per b,i; 256 threads, lane=c):
//   z[j,c] = BW[c] + sum_h inv[h,j]*(SG[h,i,c] + w[h,j]*DG[h,j,c] - mu[h,j]*GW[h,c])
//   value[b,i,j] = sum_c leaky(z)*W_f2[c]
// ---------------------------------------------------------------------------
__global__ __launch_bounds__(256) void kC(
    const float* __restrict__ SG, const float* __restrict__ DG,
    const float* __restrict__ sumS, const float* __restrict__ sumS2,
    const float* __restrict__ sumD, const float* __restrict__ sumD2,
    const float* __restrict__ dotSD, const float* __restrict__ w_all,
    const float* __restrict__ GW, const float* __restrict__ BW,
    const float* __restrict__ W_f2, float* __restrict__ value)
{
    const int bi = blockIdx.x;
    const int b  = bi >> 5;
    const int i  = bi & 31;
    const int t  = threadIdx.x;

    __shared__ float SGi[256];
    __shared__ float GWs[256];
    __shared__ float BWs[64];
    __shared__ float wf2s[64];
    __shared__ float w_s[128];
    __shared__ float mu_s[128];
    __shared__ float inv_s[128];

    {
        const int h = t >> 6, c = t & 63;
        SGi[t] = SG[((b * H + h) * N + i) * 64 + c];
        GWs[t] = GW[t];
        if (t < 64) { BWs[t] = BW[t]; wf2s[t] = W_f2[t]; }
        if (t < 128) {
            const int hh = t >> 5, j = t & 31;
            const int hi = (b * H + hh) * N + i;
            const int hj = (b * H + hh) * N + j;
            const float wv  = w_all[hi * N + j];
            const float sS  = sumS[hi],  sS2 = sumS2[hi];
            const float sD  = sumD[hj],  sD2 = sumD2[hj];
            const float dsd = dotSD[hi * N + j];
            const float mu  = (sS + wv * sD) * (1.f / 64.f);
            const float e2  = (sS2 + 2.f * wv * dsd + wv * wv * sD2) * (1.f / 64.f);
            const float var = fmaxf(e2 - mu * mu, 0.f);
            w_s[t]   = wv;
            mu_s[t]  = mu;
            inv_s[t] = rsqrtf(var + LN_EPS);
        }
    }
    __syncthreads();

    const int w0 = t >> 6;
    const int e  = t & 63;
    const float SGr0 = SGi[e],       SGr1 = SGi[64 + e];
    const float SGr2 = SGi[128 + e], SGr3 = SGi[192 + e];
    const float GW0 = GWs[e],        GW1 = GWs[64 + e];
    const float GW2 = GWs[128 + e],  GW3 = GWs[192 + e];
    const float bwr = BWs[e];
    const float f2  = wf2s[e];
    const float* DGb = DG + b * H * N * 64;

    #pragma unroll
    for (int jb = 0; jb < 8; jb++) {
        const int j = jb * 4 + w0;
        const float* DGj = DGb + j * 64 + e;
        const float d0 = DGj[0];
        const float d1 = DGj[2048];
        const float d2 = DGj[4096];
        const float d3 = DGj[6144];
        float z = bwr;
        z += inv_s[j]       * (SGr0 + w_s[j]       * d0 - mu_s[j]       * GW0);
        z += inv_s[32 + j]  * (SGr1 + w_s[32 + j]  * d1 - mu_s[32 + j]  * GW1);
        z += inv_s[64 + j]  * (SGr2 + w_s[64 + j]  * d2 - mu_s[64 + j]  * GW2);
        z += inv_s[96 + j]  * (SGr3 + w_s[96 + j]  * d3 - mu_s[96 + j]  * GW3);
        float p = leaky(z) * f2;
        #pragma unroll
        for (int m = 32; m; m >>= 1) p += __shfl_xor(p, m, 64);
        if (e == 0) value[bi * N + j] = p;
    }
}

extern "C" void kernel_launch(void* const* d_in, const int* in_sizes, int n_in,
                              void* d_out, int out_size, void* d_ws, size_t ws_size,
                              hipStream_t stream)
{
    const float* states   = (const float*)d_in[0];
    const float* policies = (const float*)d_in[1];
    const float* actions  = (const float*)d_in[2];
    const float* W_se     = (const float*)d_in[3];
    const float* b_se     = (const float*)d_in[4];
    const float* W_sape   = (const float*)d_in[5];
    const float* b_sape   = (const float*)d_in[6];
    const float* Wk       = (const float*)d_in[7];
    const float* Wq       = (const float*)d_in[8];
    const float* Wv       = (const float*)d_in[9];
    const float* ln_g     = (const float*)d_in[10];
    const float* ln_b     = (const float*)d_in[11];
    const float* W_f1     = (const float*)d_in[12];
    const float* W_f2     = (const float*)d_in[13];

    float* out_value = (float*)d_out;                 // [B,N,N,1]
    float* out_w     = out_value + B * N * N;         // [B,H,N,N]

    float* ws    = (float*)d_ws;
    float* se    = ws;                   // 524288
    float* xa    = se    + B * N * 128;  // 524288
    float* xp    = xa    + B * N * 128;  // 524288
    float* SG    = xp    + B * N * 128;  // B*H*N*64 = 1048576
    float* DG    = SG    + B * H * N * 64;  // 1048576
    float* sumS  = DG    + B * H * N * 64;  // 16384
    float* sumS2 = sumS  + B * H * N;       // 16384
    float* sumD  = sumS2 + B * H * N;       // 16384
    float* sumD2 = sumD  + B * H * N;       // 16384
    float* dotSD = sumD2 + B * H * N;       // 524288
    float* GW    = dotSD + B * H * N * N;   // 256
    float* BW    = GW    + 256;             // 64

    kW<<<1, 256, 0, stream>>>(ln_g, ln_b, W_f1, GW, BW);
    kA<<<B * N, 128, 0, stream>>>(states, policies, actions, W_se, b_se,
                                  W_sape, b_sape, se, xa, xp);
    kB<<<B * H, 512, 0, stream>>>(se, xa, xp, Wk, Wq, Wv, W_f1, ln_g, out_w,
                                  SG, DG, sumS, sumS2, sumD, sumD2, dotSD);
    kC<<<B * N, 256, 0, stream>>>(SG, DG, sumS, sumS2, sumD, sumD2, dotSD,
                                  out_w, GW, BW, W_f2, out_value);
}

// Round 3
// 196.166 us; speedup vs baseline: 2.2351x; 1.0783x over previous
//
#include <hip/hip_runtime.h>
#include <hip/hip_bf16.h>

#define B 128
#define N 32
#define DO 128
#define NA 16
#define H 4
#define DK 64
#define DV 64
#define LN_EPS 1e-5f
#define NEG_SLOPE 0.01f

__device__ __forceinline__ float leaky(float x) {
    return x >= 0.f ? x : NEG_SLOPE * x;
}

// ---------------------------------------------------------------------------
// kW: GW[h,c] = sum_e ln_g[h,e]*W_f1[h*64+e,c]; BW[c] = sum_he ln_b*W_f1
// ---------------------------------------------------------------------------
__global__ __launch_bounds__(256) void kW(
    const float* __restrict__ ln_g, const float* __restrict__ ln_b,
    const float* __restrict__ W_f1, float* __restrict__ GW, float* __restrict__ BW)
{
    const int t = threadIdx.x;
    const int h = t >> 6, c = t & 63;
    float acc = 0.f;
    for (int e = 0; e < 64; e++)
        acc += ln_g[h * 64 + e] * W_f1[(h * 64 + e) * 64 + c];
    GW[t] = acc;
    if (t < 64) {
        float a2 = 0.f;
        for (int r = 0; r < 256; r++) a2 += ln_b[r] * W_f1[r * 64 + t];
        BW[t] = a2;
    }
}

// ---------------------------------------------------------------------------
// Kernel A: 512 blocks x 128 threads; 8 rows per block (weights read once
// per 8 rows instead of once per row: 557MB -> 70MB L2 traffic)
// ---------------------------------------------------------------------------
__global__ __launch_bounds__(128) void kA(
    const float* __restrict__ states, const float* __restrict__ policies,
    const float* __restrict__ actions, const float* __restrict__ W_se,
    const float* __restrict__ b_se, const float* __restrict__ W_sape,
    const float* __restrict__ b_sape,
    float* __restrict__ se, float* __restrict__ xa, float* __restrict__ xp)
{
    const int row0 = blockIdx.x * 8;
    const int t    = threadIdx.x;

    __shared__ float s_rows[8][128];
    __shared__ float a_rows[8][16];
    __shared__ float p_rows[8][16];
    __shared__ float tail[16][128];   // W_sape rows 128..143

    {
        const float4* src = (const float4*)(states + row0 * 128);
        float4* dst = (float4*)&s_rows[0][0];
        dst[t]       = src[t];
        dst[t + 128] = src[t + 128];
        const int r = t >> 4, d = t & 15;
        a_rows[r][d] = actions[(row0 + r) * 16 + d];
        p_rows[r][d] = policies[(row0 + r) * 16 + d];
        const float4* tsrc = (const float4*)(W_sape + 128 * 128);
        float4* tdst = (float4*)&tail[0][0];
        #pragma unroll
        for (int k = 0; k < 4; k++) tdst[t + k * 128] = tsrc[t + k * 128];
    }
    __syncthreads();

    float acc_se[8] = {0,0,0,0,0,0,0,0};
    float acc_sp[8] = {0,0,0,0,0,0,0,0};
    #pragma unroll 2
    for (int d = 0; d < 128; d++) {
        const float wse = W_se[d * 128 + t];
        const float wsp = W_sape[d * 128 + t];
        #pragma unroll
        for (int r = 0; r < 8; r++) {
            const float s = s_rows[r][d];
            acc_se[r] += s * wse;
            acc_sp[r] += s * wsp;
        }
    }
    const float bse = b_se[t], bsp = b_sape[t];
    #pragma unroll
    for (int r = 0; r < 8; r++) {
        float aa = bsp + acc_sp[r];
        float pp = aa;
        #pragma unroll
        for (int d = 0; d < 16; d++) {
            const float wv = tail[d][t];
            aa += a_rows[r][d] * wv;
            pp += p_rows[r][d] * wv;
        }
        se[(row0 + r) * 128 + t] = leaky(bse + acc_se[r]);
        xa[(row0 + r) * 128 + t] = leaky(aa);
        xp[(row0 + r) * 128 + t] = leaky(pp);
    }
}

// ---------------------------------------------------------------------------
// Kernel B (per b,h; 512 threads; LDS 54016B -> 3 blocks/CU):
//   stage1: q,k = se@Wq/Wk; ava = xa@Wv (weights hoisted, 4 rows/thread)
//   stage2: ava->bufB, xp->bufA, scores; softmax (all threads) -> w_out
//   stage3: avp -> diff; S = w@ava
//   stage3b: Wg = g(.)W_f1h -> bufA
//   stage4-6: row sums, dotSD, SG/DG
// ---------------------------------------------------------------------------
#define RS 68

__global__ __launch_bounds__(512, 6) void kB(
    const float* __restrict__ se, const float* __restrict__ xa,
    const float* __restrict__ xp, const float* __restrict__ Wk,
    const float* __restrict__ Wq, const float* __restrict__ Wv,
    const float* __restrict__ W_f1, const float* __restrict__ ln_g,
    float* __restrict__ w_out,
    float* __restrict__ SG, float* __restrict__ DG,
    float* __restrict__ sumS, float* __restrict__ sumS2,
    float* __restrict__ sumD, float* __restrict__ sumD2,
    float* __restrict__ dotSD)
{
    const int bh = blockIdx.x;
    const int b  = bh >> 2;
    const int h  = bh & 3;
    const int t  = threadIdx.x;

    __shared__ float bufA[N * 128];   // se -> xp -> Wg[e][c]
    __shared__ float bufB[N * 128];   // xa; [0,2048) becomes ava[i*64+e]
    __shared__ float q_s[N * RS];     // q -> S
    __shared__ float k_s[N * RS];     // k -> diff
    __shared__ float sc[N * 33];      // scores -> w

    for (int idx = t; idx < N * 32; idx += 512) {
        ((float4*)bufA)[idx] = ((const float4*)(se + b * N * 128))[idx];
        ((float4*)bufB)[idx] = ((const float4*)(xa + b * N * 128))[idx];
    }
    __syncthreads();

    const float* Wqh = Wq + h * 128 * DK;
    const float* Wkh = Wk + h * 128 * DK;
    const float* Wvh = Wv + h * 128 * DV;

    // stage 1: 4 rows per thread, weight loads hoisted (3 loads -> 12 FMA)
    const int e  = t & 63;
    const int i0 = (t >> 6) * 4;
    float aq[4] = {0,0,0,0}, ak[4] = {0,0,0,0}, av[4] = {0,0,0,0};
    #pragma unroll 2
    for (int d = 0; d < 128; d++) {
        const float wq = Wqh[d * 64 + e];
        const float wk = Wkh[d * 64 + e];
        const float wv = Wvh[d * 64 + e];
        #pragma unroll
        for (int r = 0; r < 4; r++) {
            const float sA = bufA[(i0 + r) * 128 + d];
            const float sB = bufB[(i0 + r) * 128 + d];
            aq[r] += sA * wq;
            ak[r] += sA * wk;
            av[r] += sB * wv;
        }
    }
    #pragma unroll
    for (int r = 0; r < 4; r++) {
        q_s[(i0 + r) * RS + e] = aq[r];
        k_s[(i0 + r) * RS + e] = ak[r];
    }
    __syncthreads();  // bufA/bufB stage-1 reads done; q/k visible

    // stage 2: ava -> bufB[0:2048), xp -> bufA, scores
    #pragma unroll
    for (int r = 0; r < 4; r++) bufB[(i0 + r) * 64 + e] = av[r];
    for (int idx = t; idx < N * 32; idx += 512)
        ((float4*)bufA)[idx] = ((const float4*)(xp + b * N * 128))[idx];
    for (int o = t; o < N * N; o += 512) {
        const int i = o >> 5, j = o & 31;
        float a = 0.f;
        #pragma unroll
        for (int e4 = 0; e4 < 16; e4++) {
            const float4 qv = *(const float4*)&q_s[i * RS + e4 * 4];
            const float4 kv = *(const float4*)&k_s[j * RS + e4 * 4];
            a += qv.x * kv.x + qv.y * kv.y + qv.z * kv.z + qv.w * kv.w;
        }
        sc[i * 33 + j] = a * 0.125f;
    }
    __syncthreads();

    // stage 2b: softmax, 16 lanes per row, 2 cols per thread
    {
        const int i = t >> 4, l = t & 15;
        float v0 = sc[i * 33 + l], v1 = sc[i * 33 + 16 + l];
        float mx = fmaxf(v0, v1);
        #pragma unroll
        for (int m = 8; m; m >>= 1) mx = fmaxf(mx, __shfl_xor(mx, m));
        float e0 = __expf(v0 - mx), e1 = __expf(v1 - mx);
        float sum = e0 + e1;
        #pragma unroll
        for (int m = 8; m; m >>= 1) sum += __shfl_xor(sum, m);
        const float inv = 1.f / sum;
        e0 *= inv; e1 *= inv;
        sc[i * 33 + l]      = e0;
        sc[i * 33 + 16 + l] = e1;
        w_out[(bh * N + i) * N + l]      = e0;
        w_out[(bh * N + i) * N + 16 + l] = e1;
    }
    __syncthreads();

    // stage 3: avp -> diff (k_s); S = w@ava (q_s)
    float ap[4] = {0,0,0,0};
    #pragma unroll 4
    for (int d = 0; d < 128; d++) {
        const float wv = Wvh[d * 64 + e];
        #pragma unroll
        for (int r = 0; r < 4; r++) ap[r] += bufA[(i0 + r) * 128 + d] * wv;
    }
    float sa[4] = {0,0,0,0};
    #pragma unroll 4
    for (int k2 = 0; k2 < N; k2++) {
        const float avk = bufB[k2 * 64 + e];
        #pragma unroll
        for (int r = 0; r < 4; r++) sa[r] += sc[(i0 + r) * 33 + k2] * avk;
    }
    #pragma unroll
    for (int r = 0; r < 4; r++) {
        k_s[(i0 + r) * RS + e] = ap[r] - bufB[(i0 + r) * 64 + e];
        q_s[(i0 + r) * RS + e] = sa[r];
    }
    __syncthreads();

    // stage 3b: Wg -> bufA (xp dead)
    for (int idx = t; idx < 4096; idx += 512) {
        const int ee = idx >> 6, c = idx & 63;
        bufA[idx] = ln_g[h * 64 + ee] * W_f1[(h * 64 + ee) * 64 + c];
    }
    __syncthreads();

    // stage 4: row sums
    if (t < 64) {
        const int r = t & 31;
        const float* src = (t < 32) ? (q_s + r * RS) : (k_s + r * RS);
        float s1 = 0.f, s2 = 0.f;
        #pragma unroll
        for (int e4 = 0; e4 < 16; e4++) {
            const float4 v = *(const float4*)&src[e4 * 4];
            s1 += v.x + v.y + v.z + v.w;
            s2 += v.x * v.x + v.y * v.y + v.z * v.z + v.w * v.w;
        }
        if (t < 32) { sumS[bh * N + r] = s1; sumS2[bh * N + r] = s2; }
        else        { sumD[bh * N + r] = s1; sumD2[bh * N + r] = s2; }
    }

    // stage 5: dotSD
    for (int o = t; o < N * N; o += 512) {
        const int i = o >> 5, j = o & 31;
        float a = 0.f;
        #pragma unroll
        for (int e4 = 0; e4 < 16; e4++) {
            const float4 sv = *(const float4*)&q_s[i * RS + e4 * 4];
            const float4 dv = *(const float4*)&k_s[j * RS + e4 * 4];
            a += sv.x * dv.x + sv.y * dv.y + sv.z * dv.z + sv.w * dv.w;
        }
        dotSD[(bh * N + i) * N + j] = a;
    }

    // stage 6: SG = S@Wg, DG = diff@Wg
    for (int qo = t; qo < 1024; qo += 512) {
        const int isS = (qo < 512) ? 1 : 0;
        const int idx = qo & 511;
        const int r   = idx >> 4;
        const int c4  = (idx & 15) << 2;
        const float* src = isS ? (q_s + r * RS) : (k_s + r * RS);
        float4 acc = {0.f, 0.f, 0.f, 0.f};
        #pragma unroll 8
        for (int ee = 0; ee < 64; ee++) {
            const float s = src[ee];
            const float4 wv = *(const float4*)&bufA[ee * 64 + c4];
            acc.x += s * wv.x; acc.y += s * wv.y;
            acc.z += s * wv.z; acc.w += s * wv.w;
        }
        float* dst = (isS ? SG : DG) + (bh * N + r) * 64 + c4;
        *(float4*)dst = acc;
    }
}

// ---------------------------------------------------------------------------
// Kernel C (512 blocks: b x 4 i-groups of 8; 256 threads):
//   DG[b] read once per block (was once per i)
// ---------------------------------------------------------------------------
__global__ __launch_bounds__(256) void kC(
    const float* __restrict__ SG, const float* __restrict__ DG,
    const float* __restrict__ sumS, const float* __restrict__ sumS2,
    const float* __restrict__ sumD, const float* __restrict__ sumD2,
    const float* __restrict__ dotSD, const float* __restrict__ w_all,
    const float* __restrict__ GW, const float* __restrict__ BW,
    const float* __restrict__ W_f2, float* __restrict__ value)
{
    const int blk = blockIdx.x;
    const int b   = blk >> 2;
    const int i0  = (blk & 3) * 8;
    const int t   = threadIdx.x;

    __shared__ float SGs[8][256];
    __shared__ float GWs[256];
    __shared__ float BWs[64], wf2s[64];
    __shared__ float w_s[4][8][32];
    __shared__ float mu_s[4][8][32];
    __shared__ float inv_s[4][8][32];

    GWs[t] = GW[t];
    if (t < 64) { BWs[t] = BW[t]; wf2s[t] = W_f2[t]; }
    for (int idx4 = t; idx4 < 512; idx4 += 256) {
        const int ii  = idx4 >> 6;
        const int hc4 = idx4 & 63;
        const int hh  = hc4 >> 4, c4 = (hc4 & 15) * 4;
        ((float4*)&SGs[ii][0])[hc4] =
            *(const float4*)&SG[((b * 4 + hh) * 32 + i0 + ii) * 64 + c4];
    }
    for (int idx = t; idx < 1024; idx += 256) {
        const int hh = idx >> 8, ii = (idx >> 5) & 7, j = idx & 31;
        const int hi = (b * 4 + hh) * 32 + (i0 + ii);
        const int hj = (b * 4 + hh) * 32 + j;
        const float wv  = w_all[hi * 32 + j];
        const float dsd = dotSD[hi * 32 + j];
        const float mu  = (sumS[hi] + wv * sumD[hj]) * (1.f / 64.f);
        const float e2  = (sumS2[hi] + 2.f * wv * dsd + wv * wv * sumD2[hj]) * (1.f / 64.f);
        const float var = fmaxf(e2 - mu * mu, 0.f);
        w_s[hh][ii][j]   = wv;
        mu_s[hh][ii][j]  = mu;
        inv_s[hh][ii][j] = rsqrtf(var + LN_EPS);
    }
    __syncthreads();

    const int w0 = t >> 6;
    const int e  = t & 63;
    const float GW0 = GWs[e],       GW1 = GWs[64 + e];
    const float GW2 = GWs[128 + e], GW3 = GWs[192 + e];
    const float bwr = BWs[e], f2 = wf2s[e];
    const float* DGb = DG + b * H * N * 64;

    for (int jb = 0; jb < 8; jb++) {
        const int j = jb * 4 + w0;
        const float d0 = DGb[(0 * 32 + j) * 64 + e];
        const float d1 = DGb[(1 * 32 + j) * 64 + e];
        const float d2 = DGb[(2 * 32 + j) * 64 + e];
        const float d3 = DGb[(3 * 32 + j) * 64 + e];
        #pragma unroll
        for (int ii = 0; ii < 8; ii++) {
            float z = bwr;
            z += inv_s[0][ii][j] * (SGs[ii][e]       + w_s[0][ii][j] * d0 - mu_s[0][ii][j] * GW0);
            z += inv_s[1][ii][j] * (SGs[ii][64 + e]  + w_s[1][ii][j] * d1 - mu_s[1][ii][j] * GW1);
            z += inv_s[2][ii][j] * (SGs[ii][128 + e] + w_s[2][ii][j] * d2 - mu_s[2][ii][j] * GW2);
            z += inv_s[3][ii][j] * (SGs[ii][192 + e] + w_s[3][ii][j] * d3 - mu_s[3][ii][j] * GW3);
            float p = leaky(z) * f2;
            #pragma unroll
            for (int m = 32; m; m >>= 1) p += __shfl_xor(p, m);
            if (e == 0) value[(b * 32 + i0 + ii) * 32 + j] = p;
        }
    }
}

extern "C" void kernel_launch(void* const* d_in, const int* in_sizes, int n_in,
                              void* d_out, int out_size, void* d_ws, size_t ws_size,
                              hipStream_t stream)
{
    const float* states   = (const float*)d_in[0];
    const float* policies = (const float*)d_in[1];
    const float* actions  = (const float*)d_in[2];
    const float* W_se     = (const float*)d_in[3];
    const float* b_se     = (const float*)d_in[4];
    const float* W_sape   = (const float*)d_in[5];
    const float* b_sape   = (const float*)d_in[6];
    const float* Wk       = (const float*)d_in[7];
    const float* Wq       = (const float*)d_in[8];
    const float* Wv       = (const float*)d_in[9];
    const float* ln_g     = (const float*)d_in[10];
    const float* ln_b     = (const float*)d_in[11];
    const float* W_f1     = (const float*)d_in[12];
    const float* W_f2     = (const float*)d_in[13];

    float* out_value = (float*)d_out;
    float* out_w     = out_value + B * N * N;

    float* ws    = (float*)d_ws;
    float* se    = ws;
    float* xa    = se    + B * N * 128;
    float* xp    = xa    + B * N * 128;
    float* SG    = xp    + B * N * 128;
    float* DG    = SG    + B * H * N * 64;
    float* sumS  = DG    + B * H * N * 64;
    float* sumS2 = sumS  + B * H * N;
    float* sumD  = sumS2 + B * H * N;
    float* sumD2 = sumD  + B * H * N;
    float* dotSD = sumD2 + B * H * N;
    float* GW    = dotSD + B * H * N * N;
    float* BW    = GW    + 256;

    kW<<<1, 256, 0, stream>>>(ln_g, ln_b, W_f1, GW, BW);
    kA<<<512, 128, 0, stream>>>(states, policies, actions, W_se, b_se,
                                W_sape, b_sape, se, xa, xp);
    kB<<<B * H, 512, 0, stream>>>(se, xa, xp, Wk, Wq, Wv, W_f1, ln_g, out_w,
                                  SG, DG, sumS, sumS2, sumD, sumD2, dotSD);
    kC<<<512, 256, 0, stream>>>(SG, DG, sumS, sumS2, sumD, sumD2, dotSD,
                                out_w, GW, BW, W_f2, out_value);
}

// Round 4
// 179.385 us; speedup vs baseline: 2.4442x; 1.0935x over previous
//
#include <hip/hip_runtime.h>
#include <hip/hip_bf16.h>

#define B 128
#define N 32
#define DO 128
#define NA 16
#define H 4
#define DK 64
#define DV 64
#define LN_EPS 1e-5f
#define NEG_SLOPE 0.01f

__device__ __forceinline__ float leaky(float x) {
    return x >= 0.f ? x : NEG_SLOPE * x;
}

// ---------------------------------------------------------------------------
// Kernel A: 512 blocks x 128 threads; 8 rows per block
// ---------------------------------------------------------------------------
__global__ __launch_bounds__(128) void kA(
    const float* __restrict__ states, const float* __restrict__ policies,
    const float* __restrict__ actions, const float* __restrict__ W_se,
    const float* __restrict__ b_se, const float* __restrict__ W_sape,
    const float* __restrict__ b_sape,
    float* __restrict__ se, float* __restrict__ xa, float* __restrict__ xp)
{
    const int row0 = blockIdx.x * 8;
    const int t    = threadIdx.x;

    __shared__ float s_rows[8][128];
    __shared__ float a_rows[8][16];
    __shared__ float p_rows[8][16];
    __shared__ float tail[16][128];   // W_sape rows 128..143

    {
        const float4* src = (const float4*)(states + row0 * 128);
        float4* dst = (float4*)&s_rows[0][0];
        dst[t]       = src[t];
        dst[t + 128] = src[t + 128];
        const int r = t >> 4, d = t & 15;
        a_rows[r][d] = actions[(row0 + r) * 16 + d];
        p_rows[r][d] = policies[(row0 + r) * 16 + d];
        const float4* tsrc = (const float4*)(W_sape + 128 * 128);
        float4* tdst = (float4*)&tail[0][0];
        #pragma unroll
        for (int k = 0; k < 4; k++) tdst[t + k * 128] = tsrc[t + k * 128];
    }
    __syncthreads();

    float acc_se[8] = {0,0,0,0,0,0,0,0};
    float acc_sp[8] = {0,0,0,0,0,0,0,0};
    #pragma unroll 4
    for (int d = 0; d < 128; d++) {
        const float wse = W_se[d * 128 + t];
        const float wsp = W_sape[d * 128 + t];
        #pragma unroll
        for (int r = 0; r < 8; r++) {
            const float s = s_rows[r][d];
            acc_se[r] += s * wse;
            acc_sp[r] += s * wsp;
        }
    }
    const float bse = b_se[t], bsp = b_sape[t];
    #pragma unroll
    for (int r = 0; r < 8; r++) {
        float aa = bsp + acc_sp[r];
        float pp = aa;
        #pragma unroll
        for (int d = 0; d < 16; d++) {
            const float wv = tail[d][t];
            aa += a_rows[r][d] * wv;
            pp += p_rows[r][d] * wv;
        }
        se[(row0 + r) * 128 + t] = leaky(bse + acc_se[r]);
        xa[(row0 + r) * 128 + t] = leaky(aa);
        xp[(row0 + r) * 128 + t] = leaky(pp);
    }
}

// ---------------------------------------------------------------------------
// Kernel B (per b,h; 512 threads; LDS 54,272B == 3 blocks/CU limit):
//   stage1: q,k = se@Wq/Wk; ava = xa@Wv (weights hoisted, 4 rows/thread)
//   stage2: ava->bufB, xp->bufA, scores; softmax -> w_out
//   stage3: avp -> diff; S = w@ava;  3b: Wg -> bufA
//   stage4-6: row sums + GW (threads 64-127), dotSD, SG/DG
// ---------------------------------------------------------------------------
#define RS 68

__global__ __launch_bounds__(512, 6) void kB(
    const float* __restrict__ se, const float* __restrict__ xa,
    const float* __restrict__ xp, const float* __restrict__ Wk,
    const float* __restrict__ Wq, const float* __restrict__ Wv,
    const float* __restrict__ W_f1, const float* __restrict__ ln_g,
    float* __restrict__ w_out,
    float* __restrict__ SG, float* __restrict__ DG,
    float* __restrict__ sumS, float* __restrict__ sumS2,
    float* __restrict__ sumD, float* __restrict__ sumD2,
    float* __restrict__ dotSD, float* __restrict__ GW)
{
    const int bh = blockIdx.x;
    const int b  = bh >> 2;
    const int h  = bh & 3;
    const int t  = threadIdx.x;

    __shared__ float bufA[N * 128];   // se -> xp -> Wg[e][c]
    __shared__ float bufB[N * 128];   // xa; [0,2048) becomes ava[i*64+e]
    __shared__ float q_s[N * RS];     // q -> S
    __shared__ float k_s[N * RS];     // k -> diff
    __shared__ float sc[N * 32];      // scores -> w  (stride 32: LDS budget)

    for (int idx = t; idx < N * 32; idx += 512) {
        ((float4*)bufA)[idx] = ((const float4*)(se + b * N * 128))[idx];
        ((float4*)bufB)[idx] = ((const float4*)(xa + b * N * 128))[idx];
    }
    __syncthreads();

    const float* Wqh = Wq + h * 128 * DK;
    const float* Wkh = Wk + h * 128 * DK;
    const float* Wvh = Wv + h * 128 * DV;

    // stage 1: 4 rows per thread, weight loads hoisted
    const int e  = t & 63;
    const int i0 = (t >> 6) * 4;
    float aq[4] = {0,0,0,0}, ak[4] = {0,0,0,0}, av[4] = {0,0,0,0};
    #pragma unroll 4
    for (int d = 0; d < 128; d++) {
        const float wq = Wqh[d * 64 + e];
        const float wk = Wkh[d * 64 + e];
        const float wv = Wvh[d * 64 + e];
        #pragma unroll
        for (int r = 0; r < 4; r++) {
            const float sA = bufA[(i0 + r) * 128 + d];
            const float sB = bufB[(i0 + r) * 128 + d];
            aq[r] += sA * wq;
            ak[r] += sA * wk;
            av[r] += sB * wv;
        }
    }
    #pragma unroll
    for (int r = 0; r < 4; r++) {
        q_s[(i0 + r) * RS + e] = aq[r];
        k_s[(i0 + r) * RS + e] = ak[r];
    }
    __syncthreads();

    // stage 2: ava -> bufB[0:2048), xp -> bufA, scores
    #pragma unroll
    for (int r = 0; r < 4; r++) bufB[(i0 + r) * 64 + e] = av[r];
    for (int idx = t; idx < N * 32; idx += 512)
        ((float4*)bufA)[idx] = ((const float4*)(xp + b * N * 128))[idx];
    for (int o = t; o < N * N; o += 512) {
        const int i = o >> 5, j = o & 31;
        float a = 0.f;
        #pragma unroll
        for (int e4 = 0; e4 < 16; e4++) {
            const float4 qv = *(const float4*)&q_s[i * RS + e4 * 4];
            const float4 kv = *(const float4*)&k_s[j * RS + e4 * 4];
            a += qv.x * kv.x + qv.y * kv.y + qv.z * kv.z + qv.w * kv.w;
        }
        sc[i * 32 + j] = a * 0.125f;
    }
    __syncthreads();

    // stage 2b: softmax, 16 lanes per row, 2 cols per thread
    {
        const int i = t >> 4, l = t & 15;
        float v0 = sc[i * 32 + l], v1 = sc[i * 32 + 16 + l];
        float mx = fmaxf(v0, v1);
        #pragma unroll
        for (int m = 8; m; m >>= 1) mx = fmaxf(mx, __shfl_xor(mx, m));
        float e0 = __expf(v0 - mx), e1 = __expf(v1 - mx);
        float sum = e0 + e1;
        #pragma unroll
        for (int m = 8; m; m >>= 1) sum += __shfl_xor(sum, m);
        const float inv = 1.f / sum;
        e0 *= inv; e1 *= inv;
        sc[i * 32 + l]      = e0;
        sc[i * 32 + 16 + l] = e1;
        w_out[(bh * N + i) * N + l]      = e0;
        w_out[(bh * N + i) * N + 16 + l] = e1;
    }
    __syncthreads();

    // stage 3: avp -> diff (k_s); S = w@ava (q_s)
    float ap[4] = {0,0,0,0};
    #pragma unroll 4
    for (int d = 0; d < 128; d++) {
        const float wv = Wvh[d * 64 + e];
        #pragma unroll
        for (int r = 0; r < 4; r++) ap[r] += bufA[(i0 + r) * 128 + d] * wv;
    }
    float sa[4] = {0,0,0,0};
    #pragma unroll 4
    for (int k2 = 0; k2 < N; k2++) {
        const float avk = bufB[k2 * 64 + e];
        #pragma unroll
        for (int r = 0; r < 4; r++) sa[r] += sc[(i0 + r) * 32 + k2] * avk;
    }
    #pragma unroll
    for (int r = 0; r < 4; r++) {
        k_s[(i0 + r) * RS + e] = ap[r] - bufB[(i0 + r) * 64 + e];
        q_s[(i0 + r) * RS + e] = sa[r];
    }
    __syncthreads();

    // stage 3b: Wg -> bufA (xp dead)
    for (int idx = t; idx < 4096; idx += 512) {
        const int ee = idx >> 6, c = idx & 63;
        bufA[idx] = ln_g[h * 64 + ee] * W_f1[(h * 64 + ee) * 64 + c];
    }
    __syncthreads();

    // stage 4: row sums (t<64) + GW column sums (64<=t<128, redundant x128)
    if (t < 64) {
        const int r = t & 31;
        const float* src = (t < 32) ? (q_s + r * RS) : (k_s + r * RS);
        float s1 = 0.f, s2 = 0.f;
        #pragma unroll
        for (int e4 = 0; e4 < 16; e4++) {
            const float4 v = *(const float4*)&src[e4 * 4];
            s1 += v.x + v.y + v.z + v.w;
            s2 += v.x * v.x + v.y * v.y + v.z * v.z + v.w * v.w;
        }
        if (t < 32) { sumS[bh * N + r] = s1; sumS2[bh * N + r] = s2; }
        else        { sumD[bh * N + r] = s1; sumD2[bh * N + r] = s2; }
    } else if (t < 128) {
        const int c = t - 64;
        float g = 0.f;
        #pragma unroll 8
        for (int ee = 0; ee < 64; ee++) g += bufA[ee * 64 + c];
        GW[h * 64 + c] = g;
    }

    // stage 5: dotSD
    for (int o = t; o < N * N; o += 512) {
        const int i = o >> 5, j = o & 31;
        float a = 0.f;
        #pragma unroll
        for (int e4 = 0; e4 < 16; e4++) {
            const float4 sv = *(const float4*)&q_s[i * RS + e4 * 4];
            const float4 dv = *(const float4*)&k_s[j * RS + e4 * 4];
            a += sv.x * dv.x + sv.y * dv.y + sv.z * dv.z + sv.w * dv.w;
        }
        dotSD[(bh * N + i) * N + j] = a;
    }

    // stage 6: SG = S@Wg, DG = diff@Wg
    for (int qo = t; qo < 1024; qo += 512) {
        const int isS = (qo < 512) ? 1 : 0;
        const int idx = qo & 511;
        const int r   = idx >> 4;
        const int c4  = (idx & 15) << 2;
        const float* src = isS ? (q_s + r * RS) : (k_s + r * RS);
        float4 acc = {0.f, 0.f, 0.f, 0.f};
        #pragma unroll 8
        for (int ee = 0; ee < 64; ee++) {
            const float s = src[ee];
            const float4 wv = *(const float4*)&bufA[ee * 64 + c4];
            acc.x += s * wv.x; acc.y += s * wv.y;
            acc.z += s * wv.z; acc.w += s * wv.w;
        }
        float* dst = (isS ? SG : DG) + (bh * N + r) * 64 + c4;
        *(float4*)dst = acc;
    }
}

// ---------------------------------------------------------------------------
// Kernel C (512 blocks: b x 4 i-groups of 8; 256 threads)
//   BW computed per-block (redundant, replaces serial kW)
// ---------------------------------------------------------------------------
__global__ __launch_bounds__(256) void kC(
    const float* __restrict__ SG, const float* __restrict__ DG,
    const float* __restrict__ sumS, const float* __restrict__ sumS2,
    const float* __restrict__ sumD, const float* __restrict__ sumD2,
    const float* __restrict__ dotSD, const float* __restrict__ w_all,
    const float* __restrict__ GW, const float* __restrict__ ln_b,
    const float* __restrict__ W_f1, const float* __restrict__ W_f2,
    float* __restrict__ value)
{
    const int blk = blockIdx.x;
    const int b   = blk >> 2;
    const int i0  = (blk & 3) * 8;
    const int t   = threadIdx.x;

    __shared__ float SGs[8][256];
    __shared__ float GWs[256];
    __shared__ float BWs[64], wf2s[64];
    __shared__ float bwp[4][64];
    __shared__ float w_s[4][8][32];
    __shared__ float mu_s[4][8][32];
    __shared__ float inv_s[4][8][32];

    // BW partials: thread (q = t>>6, c = t&63) covers rows q*64..q*64+63
    {
        const int c = t & 63, qq = t >> 6;
        float bacc = 0.f;
        #pragma unroll 4
        for (int r = 0; r < 64; r++)
            bacc += ln_b[qq * 64 + r] * W_f1[(qq * 64 + r) * 64 + c];
        bwp[qq][c] = bacc;
    }

    GWs[t] = GW[t];
    if (t < 64) wf2s[t] = W_f2[t];
    for (int idx4 = t; idx4 < 512; idx4 += 256) {
        const int ii  = idx4 >> 6;
        const int hc4 = idx4 & 63;
        const int hh  = hc4 >> 4, c4 = (hc4 & 15) * 4;
        ((float4*)&SGs[ii][0])[hc4] =
            *(const float4*)&SG[((b * 4 + hh) * 32 + i0 + ii) * 64 + c4];
    }
    for (int idx = t; idx < 1024; idx += 256) {
        const int hh = idx >> 8, ii = (idx >> 5) & 7, j = idx & 31;
        const int hi = (b * 4 + hh) * 32 + (i0 + ii);
        const int hj = (b * 4 + hh) * 32 + j;
        const float wv  = w_all[hi * 32 + j];
        const float dsd = dotSD[hi * 32 + j];
        const float mu  = (sumS[hi] + wv * sumD[hj]) * (1.f / 64.f);
        const float e2  = (sumS2[hi] + 2.f * wv * dsd + wv * wv * sumD2[hj]) * (1.f / 64.f);
        const float var = fmaxf(e2 - mu * mu, 0.f);
        w_s[hh][ii][j]   = wv;
        mu_s[hh][ii][j]  = mu;
        inv_s[hh][ii][j] = rsqrtf(var + LN_EPS);
    }
    __syncthreads();
    if (t < 64) BWs[t] = bwp[0][t] + bwp[1][t] + bwp[2][t] + bwp[3][t];
    __syncthreads();

    const int w0 = t >> 6;
    const int e  = t & 63;
    const float GW0 = GWs[e],       GW1 = GWs[64 + e];
    const float GW2 = GWs[128 + e], GW3 = GWs[192 + e];
    const float bwr = BWs[e], f2 = wf2s[e];
    const float* DGb = DG + b * H * N * 64;

    for (int jb = 0; jb < 8; jb++) {
        const int j = jb * 4 + w0;
        const float d0 = DGb[(0 * 32 + j) * 64 + e];
        const float d1 = DGb[(1 * 32 + j) * 64 + e];
        const float d2 = DGb[(2 * 32 + j) * 64 + e];
        const float d3 = DGb[(3 * 32 + j) * 64 + e];
        #pragma unroll
        for (int ii = 0; ii < 8; ii++) {
            float z = bwr;
            z += inv_s[0][ii][j] * (SGs[ii][e]       + w_s[0][ii][j] * d0 - mu_s[0][ii][j] * GW0);
            z += inv_s[1][ii][j] * (SGs[ii][64 + e]  + w_s[1][ii][j] * d1 - mu_s[1][ii][j] * GW1);
            z += inv_s[2][ii][j] * (SGs[ii][128 + e] + w_s[2][ii][j] * d2 - mu_s[2][ii][j] * GW2);
            z += inv_s[3][ii][j] * (SGs[ii][192 + e] + w_s[3][ii][j] * d3 - mu_s[3][ii][j] * GW3);
            float p = leaky(z) * f2;
            #pragma unroll
            for (int m = 32; m; m >>= 1) p += __shfl_xor(p, m);
            if (e == 0) value[(b * 32 + i0 + ii) * 32 + j] = p;
        }
    }
}

extern "C" void kernel_launch(void* const* d_in, const int* in_sizes, int n_in,
                              void* d_out, int out_size, void* d_ws, size_t ws_size,
                              hipStream_t stream)
{
    const float* states   = (const float*)d_in[0];
    const float* policies = (const float*)d_in[1];
    const float* actions  = (const float*)d_in[2];
    const float* W_se     = (const float*)d_in[3];
    const float* b_se     = (const float*)d_in[4];
    const float* W_sape   = (const float*)d_in[5];
    const float* b_sape   = (const float*)d_in[6];
    const float* Wk       = (const float*)d_in[7];
    const float* Wq       = (const float*)d_in[8];
    const float* Wv       = (const float*)d_in[9];
    const float* ln_g     = (const float*)d_in[10];
    const float* ln_b     = (const float*)d_in[11];
    const float* W_f1     = (const float*)d_in[12];
    const float* W_f2     = (const float*)d_in[13];

    float* out_value = (float*)d_out;
    float* out_w     = out_value + B * N * N;

    float* ws    = (float*)d_ws;
    float* se    = ws;
    float* xa    = se    + B * N * 128;
    float* xp    = xa    + B * N * 128;
    float* SG    = xp    + B * N * 128;
    float* DG    = SG    + B * H * N * 64;
    float* sumS  = DG    + B * H * N * 64;
    float* sumS2 = sumS  + B * H * N;
    float* sumD  = sumS2 + B * H * N;
    float* sumD2 = sumD  + B * H * N;
    float* dotSD = sumD2 + B * H * N;
    float* GW    = dotSD + B * H * N * N;

    kA<<<512, 128, 0, stream>>>(states, policies, actions, W_se, b_se,
                                W_sape, b_sape, se, xa, xp);
    kB<<<B * H, 512, 0, stream>>>(se, xa, xp, Wk, Wq, Wv, W_f1, ln_g, out_w,
                                  SG, DG, sumS, sumS2, sumD, sumD2, dotSD, GW);
    kC<<<512, 256, 0, stream>>>(SG, DG, sumS, sumS2, sumD, sumD2, dotSD,
                                out_w, GW, ln_b, W_f1, W_f2, out_value);
}